// Round 13
// baseline (8199.503 us; speedup 1.0000x reference)
//
#include <hip/hip_runtime.h>

#define HSTEPS 8640
#define HID 128
#define BATCH 16
#define NTHR 512
#define YRING 192
#define INV127 (1.0f / 127.0f)

typedef __attribute__((ext_vector_type(4))) int i32x4;

static __device__ __forceinline__ float sigm(float x) {
    return __builtin_amdgcn_rcpf(1.0f + __expf(-x));
}
template <int CTRL>
static __device__ __forceinline__ float dppmov(float x) {
    return __int_as_float(
        __builtin_amdgcn_mov_dpp(__float_as_int(x), CTRL, 0xF, 0xF, false));
}
// sum of 8-periodic values -> every lane holds its 8-group total
static __device__ __forceinline__ float sum8(float x) {
    x += dppmov<0x121>(x);
    x += dppmov<0x122>(x);
    x += dppmov<0x124>(x);
    return x;
}
// full wave64 sum -> total lands in lane 63
static __device__ __forceinline__ float red_wave(float x) {
    x += dppmov<0x121>(x);
    x += dppmov<0x122>(x);
    x += dppmov<0x124>(x);
    x += dppmov<0x128>(x);
    float t1 = __int_as_float(__builtin_amdgcn_update_dpp(
        0, __float_as_int(x), 0x142 /*row_bcast15*/, 0xA, 0xF, false));
    x += t1;
    float t2 = __int_as_float(__builtin_amdgcn_update_dpp(
        0, __float_as_int(x), 0x143 /*row_bcast31*/, 0xC, 0xF, false));
    x += t2;
    return x;
}
// wave64 max (values >= 0) -> lane 63 holds the wave max
static __device__ __forceinline__ float maxwave(float x) {
    x = fmaxf(x, dppmov<0x121>(x));
    x = fmaxf(x, dppmov<0x122>(x));
    x = fmaxf(x, dppmov<0x124>(x));
    x = fmaxf(x, dppmov<0x128>(x));
    float t1 = __int_as_float(__builtin_amdgcn_update_dpp(
        0, __float_as_int(x), 0x142, 0xA, 0xF, false));
    x = fmaxf(x, t1);
    float t2 = __int_as_float(__builtin_amdgcn_update_dpp(
        0, __float_as_int(x), 0x143, 0xC, 0xF, false));
    x = fmaxf(x, t2);
    return x;
}
// lane^16 exchange via ds_swizzle BitMode (used in quantrow only)
static __device__ __forceinline__ float swzx16(float x) {
    return __int_as_float(
        __builtin_amdgcn_ds_swizzle(__float_as_int(x), 0x401F));
}

static __device__ __forceinline__ int pack4(const float* v, float inv) {
    int a = (int)__builtin_rintf(v[0] * inv);
    int b = (int)__builtin_rintf(v[1] * inv);
    int c = (int)__builtin_rintf(v[2] * inv);
    int d = (int)__builtin_rintf(v[3] * inv);
    return (a & 0xff) | ((b & 0xff) << 8) | ((c & 0xff) << 16) |
           ((d & 0xff) << 24);
}

// Quantize this lane's K-slices of one gate row to i8 with a per-row scale.
static __device__ __forceinline__ void quantrow(const float* rp, int grp,
                                                i32x4& f0, i32x4& f1,
                                                float& sw) {
    float v[32];
#pragma unroll
    for (int j = 0; j < 16; ++j) v[j] = rp[16 * grp + j];
#pragma unroll
    for (int j = 0; j < 16; ++j) v[16 + j] = rp[64 + 16 * grp + j];
    float mx = 1e-20f;
#pragma unroll
    for (int j = 0; j < 32; ++j) mx = fmaxf(mx, __builtin_fabsf(v[j]));
    mx = fmaxf(mx, swzx16(mx));
    mx = fmaxf(mx, __shfl_xor(mx, 32, 64));
    float inv = 127.0f / mx;
    sw = mx * INV127;
    f0 = i32x4{pack4(v, inv), pack4(v + 4, inv), pack4(v + 8, inv),
               pack4(v + 12, inv)};
    f1 = i32x4{pack4(v + 16, inv), pack4(v + 20, inv), pack4(v + 24, inv),
               pack4(v + 28, inv)};
}

#define CH2(Q, A0, A1, FA, FB)                                                \
    Q = __builtin_amdgcn_mfma_i32_16x16x64_i8((A0), FA, zqi, 0, 0, 0);        \
    Q = __builtin_amdgcn_mfma_i32_16x16x64_i8((A1), FB, (Q), 0, 0, 0);

// Uniform-wave scheme: 8 waves x 16 elements each, end-to-end. Wave w, lane
// l: element e = 16w + (l&15); holds rows {128g+e, g=0..3} of Whh0, Wih1,
// Whh1 as 24 i8 fragments (96 regs). MFMA acc reg0 is replicated across the
// 4 k-groups -> every lane owns ALL FOUR gates of its element in-register:
// acts are fully in-lane (no exchanges). Rotation: Whh0@h0n for step s+1
// issues in half2 of s. 2 barriers/step; i8 per-row-scale numerics (proven).
__global__ __launch_bounds__(NTHR, 2) void lstm2_kernel(
    const float* __restrict__ y0, const float* __restrict__ h0in,
    const float* __restrict__ c0in, const float* __restrict__ Wih0,
    const float* __restrict__ Whh0, const float* __restrict__ bih0,
    const float* __restrict__ bhh0, const float* __restrict__ Wih1,
    const float* __restrict__ Whh1, const float* __restrict__ bih1,
    const float* __restrict__ bhh1, const float* __restrict__ fcw,
    const float* __restrict__ fcb, float* __restrict__ out) {
    const int b = blockIdx.x;
    const int t = threadIdx.x;
    const int w = t >> 6;
    const int ln = t & 63;
    const int grp = ln >> 4;
    const int ln15 = ln & 15;
    const int e = 16 * w + ln15;  // this lane's element 0..127

    // hsm8 bytes: [0..127]=h0 buf0, [128..255]=h0 buf1,
    //             [256..383]=h1 buf0, [384..511]=h1 buf1
    __shared__ __align__(16) char hsm8[512];
    __shared__ float ypartbuf[8];
    __shared__ float maxb[8];
    __shared__ float ybuf[YRING];

    const i32x4 zqi = {0, 0, 0, 0};

    // ---- fragments: rows 128g+e of each matrix, 2 K-chunks each ----
    i32x4 F00a, F00b, F01a, F01b, F02a, F02b, F03a, F03b;  // Whh0
    i32x4 F10a, F10b, F11a, F11b, F12a, F12b, F13a, F13b;  // Wih1
    i32x4 F20a, F20b, F21a, F21b, F22a, F22b, F23a, F23b;  // Whh1
    float SA0, SA1, SA2, SA3, SC0, SC1, SC2, SC3, SB0, SB1, SB2, SB3;
    quantrow(Whh0 + (size_t)(e)*HID, grp, F00a, F00b, SA0);
    quantrow(Whh0 + (size_t)(128 + e) * HID, grp, F01a, F01b, SA1);
    quantrow(Whh0 + (size_t)(256 + e) * HID, grp, F02a, F02b, SA2);
    quantrow(Whh0 + (size_t)(384 + e) * HID, grp, F03a, F03b, SA3);
    quantrow(Wih1 + (size_t)(e)*HID, grp, F10a, F10b, SC0);
    quantrow(Wih1 + (size_t)(128 + e) * HID, grp, F11a, F11b, SC1);
    quantrow(Wih1 + (size_t)(256 + e) * HID, grp, F12a, F12b, SC2);
    quantrow(Wih1 + (size_t)(384 + e) * HID, grp, F13a, F13b, SC3);
    quantrow(Whh1 + (size_t)(e)*HID, grp, F20a, F20b, SB0);
    quantrow(Whh1 + (size_t)(128 + e) * HID, grp, F21a, F21b, SB1);
    quantrow(Whh1 + (size_t)(256 + e) * HID, grp, F22a, F22b, SB2);
    quantrow(Whh1 + (size_t)(384 + e) * HID, grp, F23a, F23b, SB3);
    // Wih1 always consumes tanh-bounded h0n (scale 1/127): fold now
    SC0 *= INV127;
    SC1 *= INV127;
    SC2 *= INV127;
    SC3 *= INV127;

    const float bias0_0 = bih0[e] + bhh0[e];
    const float bias0_1 = bih0[128 + e] + bhh0[128 + e];
    const float bias0_2 = bih0[256 + e] + bhh0[256 + e];
    const float bias0_3 = bih0[384 + e] + bhh0[384 + e];
    const float bias1_0 = bih1[e] + bhh1[e];
    const float bias1_1 = bih1[128 + e] + bhh1[128 + e];
    const float bias1_2 = bih1[256 + e] + bhh1[256 + e];
    const float bias1_3 = bih1[384 + e] + bhh1[384 + e];
    const float wi0_0 = Wih0[e];
    const float wi0_1 = Wih0[128 + e];
    const float wi0_2 = Wih0[256 + e];
    const float wi0_3 = Wih0[384 + e];
    const float fcb_ = fcb[0];
    const float fcw_e = fcw[e];

    float c0v = c0in[b * HID + e];            // replicated across k-groups
    float c1v = c0in[(BATCH + b) * HID + e];  // replicated across k-groups

    // ---- prologue: stage initial h (dynamic block scales) ----
    float hv_ = 0.f;
    if (t < 128) hv_ = h0in[b * HID + t];
    else if (t < 256) hv_ = h0in[(BATCH + b) * HID + (t - 128)];
    float am = maxwave(__builtin_fabsf(hv_));
    if (ln == 63) maxb[w] = am;
    if (t < 8) ypartbuf[t] = (t == 0) ? (y0[b] - fcb_) : 0.0f;
    __syncthreads();
    const float bm0 = fmaxf(fmaxf(maxb[0], maxb[1]), 1e-20f);
    const float bm1 = fmaxf(fmaxf(maxb[2], maxb[3]), 1e-20f);
    if (t < 128)
        hsm8[t] = (char)(int)__builtin_rintf(hv_ * (127.0f / bm0));
    else if (t < 256)
        hsm8[256 + (t - 128)] = (char)(int)__builtin_rintf(hv_ * (127.0f / bm1));
    __syncthreads();

    // live scales include the h-quant scale (initial h uses bm0/bm1)
    float SAq0 = SA0 * (bm0 * INV127), SAq1 = SA1 * (bm0 * INV127);
    float SAq2 = SA2 * (bm0 * INV127), SAq3 = SA3 * (bm0 * INV127);
    float SBq0 = SB0 * (bm1 * INV127), SBq1 = SB1 * (bm1 * INV127);
    float SBq2 = SB2 * (bm1 * INV127), SBq3 = SB3 * (bm1 * INV127);

    float* outb = out + (size_t)b * HSTEPS;

    // ---- prologue: QA = Whh0 @ h0_in(0) (rotation pre-work) ----
    i32x4 QA0, QA1, QA2, QA3;
    {
        const char* ap = hsm8 + 16 * grp;
        i32x4 a0 = *(const i32x4*)(ap);
        i32x4 a1 = *(const i32x4*)(ap + 64);
        CH2(QA0, a0, a1, F00a, F00b)
        CH2(QA1, a0, a1, F01a, F01b)
        CH2(QA2, a0, a1, F02a, F02b)
        CH2(QA3, a0, a1, F03a, F03b)
    }
    i32x4 QB0, QB1, QB2, QB3;

    int p = 0;
    int ys = 0;
    int flush_at = YRING;

#pragma unroll 1
    for (int s = 0; s < HSTEPS; ++s) {
        // ================= half 1 =================
        // y(s-1) from all 8 wave partials
        float yv = sum8(ypartbuf[ln & 7]) + fcb_;
        if (s > 0) {
            if (t == 0) ybuf[ys] = yv;
            ys = (ys == YRING - 1) ? 0 : ys + 1;
        }

        // issue QB = Whh1 @ h1_in(s) (independent of act0)
        {
            const char* h1p = hsm8 + 256 + 128 * p + 16 * grp;
            i32x4 b0_ = *(const i32x4*)(h1p);
            i32x4 b1_ = *(const i32x4*)(h1p + 64);
            CH2(QB0, b0_, b1_, F20a, F20b)
            CH2(QB1, b0_, b1_, F21a, F21b)
            CH2(QB2, b0_, b1_, F22a, F22b)
            CH2(QB3, b0_, b1_, F23a, F23b)
        }

        // act0: QA from half2(s-1) (or prologue), fully in-lane
        __builtin_amdgcn_s_setprio(1);
        float G0 = __builtin_fmaf(SAq0, (float)QA0[0],
                                  __builtin_fmaf(wi0_0, yv, bias0_0));
        float G1 = __builtin_fmaf(SAq1, (float)QA1[0],
                                  __builtin_fmaf(wi0_1, yv, bias0_1));
        float G2 = __builtin_fmaf(SAq2, (float)QA2[0],
                                  __builtin_fmaf(wi0_2, yv, bias0_2));
        float G3 = __builtin_fmaf(SAq3, (float)QA3[0],
                                  __builtin_fmaf(wi0_3, yv, bias0_3));
        float si = sigm(G0), sf = sigm(G1), so = sigm(G3);
        float tg = __builtin_fmaf(2.f, sigm(2.f * G2), -1.f);
        c0v = __builtin_fmaf(sf, c0v, si * tg);
        float h0n = so * __builtin_fmaf(2.f, sigm(2.f * c0v), -1.f);
        __builtin_amdgcn_s_setprio(0);
        if (ln < 16)
            hsm8[(p ^ 1) * 128 + e] = (char)(int)__builtin_rintf(h0n * 127.0f);
        if (s == 0) {
            SAq0 = SA0 * INV127;
            SAq1 = SA1 * INV127;
            SAq2 = SA2 * INV127;
            SAq3 = SA3 * INV127;
        }
        __syncthreads();  // B1: h0_out(s) ready

        // periodic output flush (uniform, 1/192 steps)
        if (s == flush_at) {
            if (t < YRING) outb[flush_at - YRING + t] = ybuf[t];
            flush_at += YRING;
        }

        // ================= half 2 =================
        const char* h0np = hsm8 + (p ^ 1) * 128 + 16 * grp;
        i32x4 d0 = *(const i32x4*)(h0np);
        i32x4 d1 = *(const i32x4*)(h0np + 64);
        // QC = Wih1 @ h0n (act1 input) -- issue FIRST
        i32x4 QC0, QC1, QC2, QC3;
        CH2(QC0, d0, d1, F10a, F10b)
        CH2(QC1, d0, d1, F11a, F11b)
        CH2(QC2, d0, d1, F12a, F12b)
        CH2(QC3, d0, d1, F13a, F13b)
        // QA = Whh0 @ h0n (pre-work for step s+1) -- fills the pipe
        CH2(QA0, d0, d1, F00a, F00b)
        CH2(QA1, d0, d1, F01a, F01b)
        CH2(QA2, d0, d1, F02a, F02b)
        CH2(QA3, d0, d1, F03a, F03b)

        // act1 = f(QC, QB), fully in-lane
        __builtin_amdgcn_s_setprio(1);
        float H0 = __builtin_fmaf(
            SC0, (float)QC0[0],
            __builtin_fmaf(SBq0, (float)QB0[0], bias1_0));
        float H1 = __builtin_fmaf(
            SC1, (float)QC1[0],
            __builtin_fmaf(SBq1, (float)QB1[0], bias1_1));
        float H2 = __builtin_fmaf(
            SC2, (float)QC2[0],
            __builtin_fmaf(SBq2, (float)QB2[0], bias1_2));
        float H3 = __builtin_fmaf(
            SC3, (float)QC3[0],
            __builtin_fmaf(SBq3, (float)QB3[0], bias1_3));
        float ti = sigm(H0), tf = sigm(H1), to = sigm(H3);
        float tg1 = __builtin_fmaf(2.f, sigm(2.f * H2), -1.f);
        c1v = __builtin_fmaf(tf, c1v, ti * tg1);
        float h1n = to * __builtin_fmaf(2.f, sigm(2.f * c1v), -1.f);
        __builtin_amdgcn_s_setprio(0);
        if (ln < 16)
            hsm8[256 + (p ^ 1) * 128 + e] =
                (char)(int)__builtin_rintf(h1n * 127.0f);

        // fused fc: one contribution per element (grp 0 lanes), wave-reduce
        float part = red_wave((ln < 16) ? fcw_e * h1n : 0.0f);
        if (ln == 63) ypartbuf[w] = part;
        if (s == 0) {
            SBq0 = SB0 * INV127;
            SBq1 = SB1 * INV127;
            SBq2 = SB2 * INV127;
            SBq3 = SB3 * INV127;
        }
        __syncthreads();  // B2: h1_out(s) + ypart ready
        p ^= 1;
    }

    // ---- tail: y(8639) + final flush ----
    float yv = sum8(ypartbuf[ln & 7]) + fcb_;
    if (t == 0) ybuf[YRING - 1] = yv;
    __syncthreads();
    if (t < YRING) outb[HSTEPS - YRING + t] = ybuf[t];
}

extern "C" void kernel_launch(void* const* d_in, const int* in_sizes, int n_in,
                              void* d_out, int out_size, void* d_ws,
                              size_t ws_size, hipStream_t stream) {
    const float* y0 = (const float*)d_in[0];
    const float* h0 = (const float*)d_in[1];
    const float* c0 = (const float*)d_in[2];
    const float* Wih0 = (const float*)d_in[3];
    const float* Whh0 = (const float*)d_in[4];
    const float* bih0 = (const float*)d_in[5];
    const float* bhh0 = (const float*)d_in[6];
    const float* Wih1 = (const float*)d_in[7];
    const float* Whh1 = (const float*)d_in[8];
    const float* bih1 = (const float*)d_in[9];
    const float* bhh1 = (const float*)d_in[10];
    const float* fcw = (const float*)d_in[11];
    const float* fcb = (const float*)d_in[12];
    float* out = (float*)d_out;

    lstm2_kernel<<<dim3(BATCH), dim3(NTHR), 0, stream>>>(
        y0, h0, c0, Wih0, Whh0, bih0, bhh0, Wih1, Whh1, bih1, bhh1, fcw, fcb,
        out);
}

// Round 14
// 6083.126 us; speedup vs baseline: 1.3479x; 1.3479x over previous
//
#include <hip/hip_runtime.h>

#define HSTEPS 8640
#define HID 128
#define BATCH 16
#define NTHR 512
#define YRING 192
#define INV127 (1.0f / 127.0f)

typedef __attribute__((ext_vector_type(4))) int i32x4;

static __device__ __forceinline__ float sigm(float x) {
    return __builtin_amdgcn_rcpf(1.0f + __expf(-x));
}
template <int CTRL>
static __device__ __forceinline__ float dppmov(float x) {
    return __int_as_float(
        __builtin_amdgcn_mov_dpp(__float_as_int(x), CTRL, 0xF, 0xF, false));
}
// sum of 4-periodic values -> every lane holds its 4-group total
static __device__ __forceinline__ float sum4(float x) {
    x += dppmov<0x121>(x);
    x += dppmov<0x122>(x);
    return x;
}
// full wave64 sum -> total lands in lane 63
static __device__ __forceinline__ float red_wave(float x) {
    x += dppmov<0x121>(x);
    x += dppmov<0x122>(x);
    x += dppmov<0x124>(x);
    x += dppmov<0x128>(x);
    float t1 = __int_as_float(__builtin_amdgcn_update_dpp(
        0, __float_as_int(x), 0x142 /*row_bcast15*/, 0xA, 0xF, false));
    x += t1;
    float t2 = __int_as_float(__builtin_amdgcn_update_dpp(
        0, __float_as_int(x), 0x143 /*row_bcast31*/, 0xC, 0xF, false));
    x += t2;
    return x;
}
// wave64 max (values >= 0) -> lane 63 holds the wave max
static __device__ __forceinline__ float maxwave(float x) {
    x = fmaxf(x, dppmov<0x121>(x));
    x = fmaxf(x, dppmov<0x122>(x));
    x = fmaxf(x, dppmov<0x124>(x));
    x = fmaxf(x, dppmov<0x128>(x));
    float t1 = __int_as_float(__builtin_amdgcn_update_dpp(
        0, __float_as_int(x), 0x142, 0xA, 0xF, false));
    x = fmaxf(x, t1);
    float t2 = __int_as_float(__builtin_amdgcn_update_dpp(
        0, __float_as_int(x), 0x143, 0xC, 0xF, false));
    x = fmaxf(x, t2);
    return x;
}
// lane^16 exchange via ds_swizzle BitMode
static __device__ __forceinline__ float swzx16(float x) {
    return __int_as_float(
        __builtin_amdgcn_ds_swizzle(__float_as_int(x), 0x401F));
}

static __device__ __forceinline__ int pack4(const float* v, float inv) {
    int a = (int)__builtin_rintf(v[0] * inv);
    int b = (int)__builtin_rintf(v[1] * inv);
    int c = (int)__builtin_rintf(v[2] * inv);
    int d = (int)__builtin_rintf(v[3] * inv);
    return (a & 0xff) | ((b & 0xff) << 8) | ((c & 0xff) << 16) |
           ((d & 0xff) << 24);
}

// Quantize one gate row to i8 with a per-row scale.
static __device__ __forceinline__ void quantrow(const float* rp, int grp,
                                                i32x4& f0, i32x4& f1,
                                                float& sw) {
    float v[32];
#pragma unroll
    for (int j = 0; j < 16; ++j) v[j] = rp[16 * grp + j];
#pragma unroll
    for (int j = 0; j < 16; ++j) v[16 + j] = rp[64 + 16 * grp + j];
    float mx = 1e-20f;
#pragma unroll
    for (int j = 0; j < 32; ++j) mx = fmaxf(mx, __builtin_fabsf(v[j]));
    mx = fmaxf(mx, swzx16(mx));
    mx = fmaxf(mx, __shfl_xor(mx, 32, 64));
    float inv = 127.0f / mx;
    sw = mx * INV127;
    f0 = i32x4{pack4(v, inv), pack4(v + 4, inv), pack4(v + 8, inv),
               pack4(v + 12, inv)};
    f1 = i32x4{pack4(v + 16, inv), pack4(v + 20, inv), pack4(v + 24, inv),
               pack4(v + 28, inv)};
}

// Quantize the SAME row index of two matrices with ONE shared scale
// (enables accumulating both products in one i32 accumulator).
static __device__ __forceinline__ void quantrow2(const float* rpA,
                                                 const float* rpB, int grp,
                                                 i32x4& a0, i32x4& a1,
                                                 i32x4& b0, i32x4& b1,
                                                 float& sw) {
    float vA[32], vB[32];
#pragma unroll
    for (int j = 0; j < 16; ++j) {
        vA[j] = rpA[16 * grp + j];
        vA[16 + j] = rpA[64 + 16 * grp + j];
        vB[j] = rpB[16 * grp + j];
        vB[16 + j] = rpB[64 + 16 * grp + j];
    }
    float mx = 1e-20f;
#pragma unroll
    for (int j = 0; j < 32; ++j) {
        mx = fmaxf(mx, __builtin_fabsf(vA[j]));
        mx = fmaxf(mx, __builtin_fabsf(vB[j]));
    }
    mx = fmaxf(mx, swzx16(mx));
    mx = fmaxf(mx, __shfl_xor(mx, 32, 64));
    float inv = 127.0f / mx;
    sw = mx * INV127;
    a0 = i32x4{pack4(vA, inv), pack4(vA + 4, inv), pack4(vA + 8, inv),
               pack4(vA + 12, inv)};
    a1 = i32x4{pack4(vA + 16, inv), pack4(vA + 20, inv), pack4(vA + 24, inv),
               pack4(vA + 28, inv)};
    b0 = i32x4{pack4(vB, inv), pack4(vB + 4, inv), pack4(vB + 8, inv),
               pack4(vB + 12, inv)};
    b1 = i32x4{pack4(vB + 16, inv), pack4(vB + 20, inv), pack4(vB + 24, inv),
               pack4(vB + 28, inv)};
}

// tile T = 2*g + jj : rows 128*g + 16*(2*gw+jj) + ln15
#define ROWOFF(T) \
    ((size_t)(128 * ((T) >> 1) + 16 * (2 * gw + ((T) & 1)) + ln15) * HID)

#define CH2(Q, A0, A1, FA, FB)                                                \
    Q = __builtin_amdgcn_mfma_i32_16x16x64_i8((A0), FA, zqi, 0, 0, 0);        \
    Q = __builtin_amdgcn_mfma_i32_16x16x64_i8((A1), FB, (Q), 0, 0, 0);
#define CH2C(Q, A0, A1, FA, FB)                                               \
    Q = __builtin_amdgcn_mfma_i32_16x16x64_i8((A0), FA, (Q), 0, 0, 0);        \
    Q = __builtin_amdgcn_mfma_i32_16x16x64_i8((A1), FB, (Q), 0, 0, 0);

// r12 structure (proven 6.60 ms) + shared-scale merged Y accumulator:
// waves 0-3 (X) = layer 0 (Whh0, act0); waves 4-7 (Y) = layer 1. Y quantizes
// Wih1/Whh1 row-pairs with ONE scale -> Whh1@h1 (half1) and Wih1@h0n (half2)
// accumulate into a single i32 accumulator set (saves 32 regs -> no spill).
// Gate-split acts: alpha lanes (ln&16==0) gates i,f; beta lanes g,o.
__global__ __launch_bounds__(NTHR, 2) void lstm2_kernel(
    const float* __restrict__ y0, const float* __restrict__ h0in,
    const float* __restrict__ c0in, const float* __restrict__ Wih0,
    const float* __restrict__ Whh0, const float* __restrict__ bih0,
    const float* __restrict__ bhh0, const float* __restrict__ Wih1,
    const float* __restrict__ Whh1, const float* __restrict__ bih1,
    const float* __restrict__ bhh1, const float* __restrict__ fcw,
    const float* __restrict__ fcb, float* __restrict__ out) {
    const int b = blockIdx.x;
    const int t = threadIdx.x;
    const int wv = t >> 6;
    const int ln = t & 63;
    const int grp = ln >> 4;   // MFMA A-operand k-slot
    const int ln15 = ln & 15;  // B col within tile
    const int gw = wv & 3;     // index within role group
    const bool isX = wv < 4;
    const int jj = ln >> 5;                  // element sub-tile 0/1
    const bool isBt = (ln & 16) != 0;        // beta lanes: gates g,o
    const int e = 32 * gw + 16 * jj + ln15;  // this lane's element
    const float foldc = isBt ? 2.0f : 1.0f;
    const int g1 = isBt ? 2 : 0;  // first owned gate (i or g)

    // hsm8 bytes: [0..127]=h0 buf0, [128..255]=h0 buf1,
    //             [256..383]=h1 buf0, [384..511]=h1 buf1
    __shared__ __align__(16) char hsm8[512];
    __shared__ float ypartbuf[4];
    __shared__ float maxb[8];
    __shared__ float ybuf[YRING];

    const i32x4 zqi = {0, 0, 0, 0};

    // ---- fragment pool: X uses Fq0..15 (Whh0); Y uses Fq0..15 (Wih1) +
    //      Fq16..31 (Whh1, shared scale with Wih1) ----
    i32x4 Fq0 = zqi, Fq1 = zqi, Fq2 = zqi, Fq3 = zqi, Fq4 = zqi, Fq5 = zqi,
          Fq6 = zqi, Fq7 = zqi, Fq8 = zqi, Fq9 = zqi, Fq10 = zqi, Fq11 = zqi,
          Fq12 = zqi, Fq13 = zqi, Fq14 = zqi, Fq15 = zqi, Fq16 = zqi,
          Fq17 = zqi, Fq18 = zqi, Fq19 = zqi, Fq20 = zqi, Fq21 = zqi,
          Fq22 = zqi, Fq23 = zqi, Fq24 = zqi, Fq25 = zqi, Fq26 = zqi,
          Fq27 = zqi, Fq28 = zqi, Fq29 = zqi, Fq30 = zqi, Fq31 = zqi;
    // accumulators: X uses Q0..7 for QA (Whh0); Y uses Q0..7 merged
    i32x4 Q0 = zqi, Q1 = zqi, Q2 = zqi, Q3 = zqi, Q4 = zqi, Q5 = zqi,
          Q6 = zqi, Q7 = zqi;
    // per-lane loop-invariant coefficients (role-dependent meaning)
    float B1c = 0, B2c = 0;    // biases for owned gates (folded)
    float E1c = 0, E2c = 0;    // X: Wih0 cols (folded); Y: E1c=fcw or 0
    float SAb1 = 0, SAb2 = 0;  // X: Whh0 base scales | Y: shared raw scales
    float SAq1 = 0, SAq2 = 0;  // live scales
    float HB1 = 0, HB2 = 0;    // Y: step-0 Whh1@h1_init float correction
    float Cst = 0;             // cell state (alpha lanes only)

    if (isX) {
        float S0, S1, S2, S3, S4, S5, S6, S7;
        quantrow(Whh0 + ROWOFF(0), grp, Fq0, Fq1, S0);
        quantrow(Whh0 + ROWOFF(1), grp, Fq2, Fq3, S1);
        quantrow(Whh0 + ROWOFF(2), grp, Fq4, Fq5, S2);
        quantrow(Whh0 + ROWOFF(3), grp, Fq6, Fq7, S3);
        quantrow(Whh0 + ROWOFF(4), grp, Fq8, Fq9, S4);
        quantrow(Whh0 + ROWOFF(5), grp, Fq10, Fq11, S5);
        quantrow(Whh0 + ROWOFF(6), grp, Fq12, Fq13, S6);
        quantrow(Whh0 + ROWOFF(7), grp, Fq14, Fq15, S7);
        SAb1 = (isBt ? (jj ? S5 : S4) : (jj ? S1 : S0)) * foldc;
        SAb2 = isBt ? (jj ? S7 : S6) : (jj ? S3 : S2);
        B1c = (bih0[g1 * 128 + e] + bhh0[g1 * 128 + e]) * foldc;
        B2c = bih0[(g1 + 1) * 128 + e] + bhh0[(g1 + 1) * 128 + e];
        E1c = Wih0[g1 * 128 + e] * foldc;
        E2c = Wih0[(g1 + 1) * 128 + e];
        Cst = isBt ? 0.f : c0in[b * HID + e];
    } else {
        float S0, S1, S2, S3, S4, S5, S6, S7;
        quantrow2(Wih1 + ROWOFF(0), Whh1 + ROWOFF(0), grp, Fq0, Fq1, Fq16,
                  Fq17, S0);
        quantrow2(Wih1 + ROWOFF(1), Whh1 + ROWOFF(1), grp, Fq2, Fq3, Fq18,
                  Fq19, S1);
        quantrow2(Wih1 + ROWOFF(2), Whh1 + ROWOFF(2), grp, Fq4, Fq5, Fq20,
                  Fq21, S2);
        quantrow2(Wih1 + ROWOFF(3), Whh1 + ROWOFF(3), grp, Fq6, Fq7, Fq22,
                  Fq23, S3);
        quantrow2(Wih1 + ROWOFF(4), Whh1 + ROWOFF(4), grp, Fq8, Fq9, Fq24,
                  Fq25, S4);
        quantrow2(Wih1 + ROWOFF(5), Whh1 + ROWOFF(5), grp, Fq10, Fq11, Fq26,
                  Fq27, S5);
        quantrow2(Wih1 + ROWOFF(6), Whh1 + ROWOFF(6), grp, Fq12, Fq13, Fq28,
                  Fq29, S6);
        quantrow2(Wih1 + ROWOFF(7), Whh1 + ROWOFF(7), grp, Fq14, Fq15, Fq30,
                  Fq31, S7);
        // raw shared scales for owned gates (foldc on first gate)
        SAb1 = (isBt ? (jj ? S5 : S4) : (jj ? S1 : S0)) * foldc;
        SAb2 = isBt ? (jj ? S7 : S6) : (jj ? S3 : S2);
        SAq1 = SAb1 * INV127;  // live scale (h at 1/127 from step 0 on)
        SAq2 = SAb2 * INV127;
        B1c = (bih1[g1 * 128 + e] + bhh1[g1 * 128 + e]) * foldc;
        B2c = bih1[(g1 + 1) * 128 + e] + bhh1[(g1 + 1) * 128 + e];
        E1c = isBt ? 0.f : fcw[e];  // fc weight (alpha lanes only)
        Cst = isBt ? 0.f : c0in[(BATCH + b) * HID + e];
    }

    const float fcb_ = fcb[0];

    // ---- prologue: stage initial h (dynamic block scales) ----
    float hv_ = 0.f;
    if (t < 128) hv_ = h0in[b * HID + t];
    else if (t < 256) hv_ = h0in[(BATCH + b) * HID + (t - 128)];
    float am = maxwave(__builtin_fabsf(hv_));
    if (ln == 63) maxb[wv] = am;
    if (t < 4) ypartbuf[t] = (t == 0) ? (y0[b] - fcb_) : 0.0f;
    __syncthreads();
    const float bm0 = fmaxf(fmaxf(maxb[0], maxb[1]), 1e-20f);
    const float bm1 = fmaxf(fmaxf(maxb[2], maxb[3]), 1e-20f);
    if (t < 128)
        hsm8[t] = (char)(int)__builtin_rintf(hv_ * (127.0f / bm0));
    else if (t < 256)
        hsm8[256 + (t - 128)] = (char)(int)__builtin_rintf(hv_ * (127.0f / bm1));
    __syncthreads();

    float* outb = out + (size_t)b * HSTEPS;

    if (isX) {
        // live scale for step-0 QA (initial h0 scale); fixed after s==0
        SAq1 = SAb1 * (bm0 * INV127);
        SAq2 = SAb2 * (bm0 * INV127);
        // X preamble: QA = Whh0 @ h0_in(0)
        i32x4 a0 = *(const i32x4*)&hsm8[16 * grp];
        i32x4 a1 = *(const i32x4*)&hsm8[64 + 16 * grp];
        CH2(Q0, a0, a1, Fq0, Fq1) CH2(Q1, a0, a1, Fq2, Fq3)
        CH2(Q2, a0, a1, Fq4, Fq5) CH2(Q3, a0, a1, Fq6, Fq7)
        CH2(Q4, a0, a1, Fq8, Fq9) CH2(Q5, a0, a1, Fq10, Fq11)
        CH2(Q6, a0, a1, Fq12, Fq13) CH2(Q7, a0, a1, Fq14, Fq15)
    } else {
        // Y preamble: throwaway Qt = Whh1 @ h1_init -> float correction HB
        i32x4 b0_ = *(const i32x4*)&hsm8[256 + 16 * grp];
        i32x4 b1_ = *(const i32x4*)&hsm8[256 + 64 + 16 * grp];
        i32x4 T0, T1, T2, T3, T4, T5, T6, T7;
        CH2(T0, b0_, b1_, Fq16, Fq17) CH2(T1, b0_, b1_, Fq18, Fq19)
        CH2(T2, b0_, b1_, Fq20, Fq21) CH2(T3, b0_, b1_, Fq22, Fq23)
        CH2(T4, b0_, b1_, Fq24, Fq25) CH2(T5, b0_, b1_, Fq26, Fq27)
        CH2(T6, b0_, b1_, Fq28, Fq29) CH2(T7, b0_, b1_, Fq30, Fq31)
        int a1s = isBt ? (jj ? T5[0] : T4[0]) : (jj ? T1[0] : T0[0]);
        int a2s = isBt ? (jj ? T7[0] : T6[0]) : (jj ? T3[0] : T2[0]);
        HB1 = SAb1 * (bm1 * INV127) * (float)a1s;
        HB2 = SAb2 * (bm1 * INV127) * (float)a2s;
        // merged accumulator must start at zero for step 0's half2
        Q0 = zqi; Q1 = zqi; Q2 = zqi; Q3 = zqi;
        Q4 = zqi; Q5 = zqi; Q6 = zqi; Q7 = zqi;
    }

    int p = 0;
    int ys = 0;
    int flush_at = YRING;

#pragma unroll 1
    for (int s = 0; s < HSTEPS; ++s) {
        // ================= half 1 =================
        if (isX) {
            // y(s-1); act0(s) [Q from half2(s-1)]; publish h0_out(s)
            float yv = sum4(ypartbuf[ln & 3]) + fcb_;
            if (s > 0) {
                if (t == 0) ybuf[ys] = yv;
                ys = (ys == YRING - 1) ? 0 : ys + 1;
            }
            int a1 = isBt ? (jj ? Q5[0] : Q4[0]) : (jj ? Q1[0] : Q0[0]);
            int a2 = isBt ? (jj ? Q7[0] : Q6[0]) : (jj ? Q3[0] : Q2[0]);
            float G1 = __builtin_fmaf(SAq1, (float)a1,
                                      __builtin_fmaf(E1c, yv, B1c));
            float G2 = __builtin_fmaf(SAq2, (float)a2,
                                      __builtin_fmaf(E2c, yv, B2c));
            float v1 = sigm(G1);  // alpha: si | beta: sigm(2*Gg)
            float v2 = sigm(G2);  // alpha: sf | beta: so
            float tg = __builtin_fmaf(2.f, swzx16(v1), -1.f);  // tanh(Gg)
            Cst = __builtin_fmaf(v2, Cst, v1 * tg);
            float v3 = sigm(2.f * Cst);
            float th = __builtin_fmaf(2.f, v3, -1.f);  // tanh(c)
            float h0n = swzx16(v2) * th;               // so * tanh(c)
            if (!(ln & 16))
                hsm8[(p ^ 1) * 128 + e] =
                    (char)(int)__builtin_rintf(h0n * 127.0f);
            if (s == 0) {
                SAq1 = SAb1 * INV127;
                SAq2 = SAb2 * INV127;
            }
        } else if (s > 0) {
            // Q = Whh1 @ h1_in(s)  (h1 at 1/127 for all s>=1)
            const char* h1p = hsm8 + 256 + 128 * p + 16 * grp;
            i32x4 b0_ = *(const i32x4*)(h1p);
            i32x4 b1_ = *(const i32x4*)(h1p + 64);
            CH2(Q0, b0_, b1_, Fq16, Fq17) CH2(Q1, b0_, b1_, Fq18, Fq19)
            CH2(Q2, b0_, b1_, Fq20, Fq21) CH2(Q3, b0_, b1_, Fq22, Fq23)
            CH2(Q4, b0_, b1_, Fq24, Fq25) CH2(Q5, b0_, b1_, Fq26, Fq27)
            CH2(Q6, b0_, b1_, Fq28, Fq29) CH2(Q7, b0_, b1_, Fq30, Fq31)
        }
        __syncthreads();  // B1: h0_out(s) ready

        // ================= half 2 =================
        if (isX) {
            if (s == flush_at) {
                if (t < YRING) outb[flush_at - YRING + t] = ybuf[t];
                flush_at += YRING;
            }
            // QA = Whh0 @ h0_out(s) (pre-work for step s+1)
            const char* h0np = hsm8 + (p ^ 1) * 128 + 16 * grp;
            i32x4 d0 = *(const i32x4*)(h0np);
            i32x4 d1 = *(const i32x4*)(h0np + 64);
            CH2(Q0, d0, d1, Fq0, Fq1) CH2(Q1, d0, d1, Fq2, Fq3)
            CH2(Q2, d0, d1, Fq4, Fq5) CH2(Q3, d0, d1, Fq6, Fq7)
            CH2(Q4, d0, d1, Fq8, Fq9) CH2(Q5, d0, d1, Fq10, Fq11)
            CH2(Q6, d0, d1, Fq12, Fq13) CH2(Q7, d0, d1, Fq14, Fq15)
        } else {
            __builtin_amdgcn_s_setprio(1);
            // Q += Wih1 @ h0_out(s); act1; publish h1_out(s), y-partial
            const char* h0np = hsm8 + (p ^ 1) * 128 + 16 * grp;
            i32x4 d0 = *(const i32x4*)(h0np);
            i32x4 d1 = *(const i32x4*)(h0np + 64);
            CH2C(Q0, d0, d1, Fq0, Fq1) CH2C(Q1, d0, d1, Fq2, Fq3)
            CH2C(Q2, d0, d1, Fq4, Fq5) CH2C(Q3, d0, d1, Fq6, Fq7)
            CH2C(Q4, d0, d1, Fq8, Fq9) CH2C(Q5, d0, d1, Fq10, Fq11)
            CH2C(Q6, d0, d1, Fq12, Fq13) CH2C(Q7, d0, d1, Fq14, Fq15)
            int a1 = isBt ? (jj ? Q5[0] : Q4[0]) : (jj ? Q1[0] : Q0[0]);
            int a2 = isBt ? (jj ? Q7[0] : Q6[0]) : (jj ? Q3[0] : Q2[0]);
            float H1 = __builtin_fmaf(SAq1, (float)a1, B1c + HB1);
            float H2 = __builtin_fmaf(SAq2, (float)a2, B2c + HB2);
            float v1 = sigm(H1);
            float v2 = sigm(H2);
            float tg = __builtin_fmaf(2.f, swzx16(v1), -1.f);
            Cst = __builtin_fmaf(v2, Cst, v1 * tg);
            float v3 = sigm(2.f * Cst);
            float th = __builtin_fmaf(2.f, v3, -1.f);
            float h1n = swzx16(v2) * th;
            __builtin_amdgcn_s_setprio(0);
            if (!(ln & 16))
                hsm8[256 + (p ^ 1) * 128 + e] =
                    (char)(int)__builtin_rintf(h1n * 127.0f);
            float part = red_wave(E1c * h1n);  // fcw on alpha, 0 on beta
            if (ln == 63) ypartbuf[gw] = part;
            if (s == 0) {
                HB1 = 0.f;
                HB2 = 0.f;
            }
        }
        __syncthreads();  // B2: h1_out(s) + ypart ready
        p ^= 1;
    }

    // ---- tail: y(8639) + final flush ----
    if (isX) {
        float yv = sum4(ypartbuf[ln & 3]) + fcb_;
        if (t == 0) ybuf[YRING - 1] = yv;
    }
    __syncthreads();
    if (t < YRING) outb[HSTEPS - YRING + t] = ybuf[t];
}

extern "C" void kernel_launch(void* const* d_in, const int* in_sizes, int n_in,
                              void* d_out, int out_size, void* d_ws,
                              size_t ws_size, hipStream_t stream) {
    const float* y0 = (const float*)d_in[0];
    const float* h0 = (const float*)d_in[1];
    const float* c0 = (const float*)d_in[2];
    const float* Wih0 = (const float*)d_in[3];
    const float* Whh0 = (const float*)d_in[4];
    const float* bih0 = (const float*)d_in[5];
    const float* bhh0 = (const float*)d_in[6];
    const float* Wih1 = (const float*)d_in[7];
    const float* Whh1 = (const float*)d_in[8];
    const float* bih1 = (const float*)d_in[9];
    const float* bhh1 = (const float*)d_in[10];
    const float* fcw = (const float*)d_in[11];
    const float* fcb = (const float*)d_in[12];
    float* out = (float*)d_out;

    lstm2_kernel<<<dim3(BATCH), dim3(NTHR), 0, stream>>>(
        y0, h0, c0, Wih0, Whh0, bih0, bhh0, Wih1, Whh1, bih1, bhh1, fcw, fcb,
        out);
}